// Round 19
// baseline (49.416 us; speedup 1.0000x reference)
//
#include <hip/hip_runtime.h>

#define NG 48
#define NT 6                    // 4 A tiles per axis (8 cells)
#define NTILES (NT * NT * NT)   // 216
#define NCH 8                   // compacted chunks per type (= gather segments)
#define CHATOMS 2048            // input atoms per chunk
#define CCAP 1024               // compacted capacity per chunk (lambda ~740)
#define SCAP 256                // per-(tile,chunk) staged cap (hot lambda ~130)
// ws layout:
//   [0, 96)            int   ccnt[3][NCH]
//   [4096, +288K)      float cpos[3][NCH][3][CCAP]    (SoA planes x,y,z)
//   [512K, +20736)     int   actc[3*216*NCH]
//   [1MiB, +10.6M)     float copies[3*216][NCH][512]
#define CPOS_OFF   4096
#define ACTC_OFF   (512u << 10)
#define COPIES_OFF (1u << 20)

__device__ __forceinline__ float type_r(int type) {
    return (type == 0) ? 1.7f : ((type == 1) ? 1.55f : 1.52f);
}

// Dispatch 1: one 512-thread block per (2048-atom slice, type). Ballot-compact
// atoms inside the grid-wide halo box into SoA planes (coalesced stride-4 for
// all later reads). Deterministic order, no atomics, counts stored plainly.
__global__ __launch_bounds__(512) void prep_kernel(
    const float* __restrict__ vC, const float* __restrict__ vN,
    const float* __restrict__ vO, int* __restrict__ ccnt,
    float* __restrict__ cpos, int natoms)
{
    const int type  = blockIdx.y;
    const int chunk = blockIdx.x;
    const float r  = type_r(type);
    const float bb = 1.5f * r + 1e-3f;
    const float* __restrict__ vecs = (type == 0) ? vC : ((type == 1) ? vN : vO);

    const int tid  = threadIdx.x;
    const int wave = tid >> 6;                 // 0..7
    const int lane = tid & 63;

    // grid-wide halo box: union over tiles of (4t-bb, 4t+3.5+bb)
    const float hi = 23.5f + bb;               // lo = -bb (vx >= 11.5 anyway)

    __shared__ int wtot[8];
    __shared__ int wbase[9];

    const int base = chunk * CHATOMS;
    const int nr   = CHATOMS / 512;            // 4 rounds

    unsigned int accept = 0u;
    float ax[4], ay[4], az[4];
    #pragma unroll
    for (int k = 0; k < nr; ++k) {
        const int a = base + (k << 9) + tid;
        bool ok = false;
        float vx = 0.f, vy = 0.f, vz = 0.f;
        if (a < natoms) {
            vx = vecs[3 * a + 0] + 23.5f;      // vec = raw + 24 - 0.5
            vy = vecs[3 * a + 1] + 23.5f;
            vz = vecs[3 * a + 2] + 23.5f;
            ok = (vx > -bb) & (vx < hi) & (vy > -bb) & (vy < hi)
               & (vz > -bb) & (vz < hi);
        }
        ax[k] = vx; ay[k] = vy; az[k] = vz;
        accept |= (ok ? 1u : 0u) << k;
    }

    int wcnt = 0;
    #pragma unroll
    for (int k = 0; k < nr; ++k)
        wcnt += (int)__popcll(__ballot((accept >> k) & 1u));
    if (lane == 0) wtot[wave] = wcnt;
    __syncthreads();
    if (tid == 0) {
        int acc = 0;
        #pragma unroll
        for (int w = 0; w < 8; ++w) { wbase[w] = acc; acc += wtot[w]; }
        wbase[8] = acc;
    }
    __syncthreads();

    float* __restrict__ cx = cpos + ((size_t)(type * NCH + chunk) * 3) * CCAP;
    float* __restrict__ cy = cx + CCAP;
    float* __restrict__ cz = cy + CCAP;

    int run = wbase[wave];
    #pragma unroll
    for (int k = 0; k < nr; ++k) {
        const unsigned long long m = __ballot((accept >> k) & 1u);
        if ((accept >> k) & 1u) {
            const int pos = run + (int)__popcll(m & ((1ull << lane) - 1ull));
            if (pos < CCAP) { cx[pos] = ax[k]; cy[pos] = ay[k]; cz[pos] = az[k]; }
        }
        run += (int)__popcll(m);
    }
    if (tid == 0) ccnt[type * NCH + chunk] = min(wbase[8], CCAP);
}

// Dispatch 2: one 128-thread block per (chunk-segment, tile, type). Scans ONLY
// the compacted chunk (coalesced SoA loads), ballot-compacts survivors to LDS,
// evaluates 4 cells/thread (R18's proven culled body), stores 512 partials.
__global__ __launch_bounds__(128) void gather_scan(
    const int* __restrict__ ccnt, const float* __restrict__ cpos,
    int* __restrict__ actc, float* __restrict__ copies)
{
    const int type = blockIdx.y;
    const int s = blockIdx.x / NTILES;        // segment(chunk)-major spread
    const int t = blockIdx.x - s * NTILES;
    const int lt = type * NTILES + t;
    const float r = type_r(type);

    const int tx = t / (NT * NT);
    const int ty = (t / NT) % NT;
    const int tz = t % NT;

    const int tid  = threadIdx.x;             // 0..127
    const int wave = tid >> 6;                // 0..1
    const int lane = tid & 63;

    const float bb  = 1.5f * r + 1e-3f;
    const float lox = 4.0f * tx - bb, hix = 4.0f * tx + 3.5f + bb;
    const float loy = 4.0f * ty - bb, hiy = 4.0f * ty + 3.5f + bb;
    const float loz = 4.0f * tz - bb, hiz = 4.0f * tz + 3.5f + bb;

    __shared__ float4 sa[SCAP];
    __shared__ int wtot[2];
    __shared__ int wbase[3];

    const float* __restrict__ cx = cpos + ((size_t)(type * NCH + s) * 3) * CCAP;
    const float* __restrict__ cy = cx + CCAP;
    const float* __restrict__ cz = cy + CCAP;
    const int n_in = ccnt[type * NCH + s];
    const int nr   = (n_in + 127) >> 7;       // <= 8 rounds

    unsigned int accept = 0u;
    float ax[8], ay[8], az[8];
    for (int k = 0; k < nr; ++k) {
        const int slot = (k << 7) + tid;
        bool ok = false;
        float vx = 0.f, vy = 0.f, vz = 0.f;
        if (slot < n_in) {
            vx = cx[slot]; vy = cy[slot]; vz = cz[slot];   // stride-4 coalesced
            ok = (vx > lox) & (vx < hix) & (vy > loy) & (vy < hiy)
               & (vz > loz) & (vz < hiz);
        }
        ax[k] = vx; ay[k] = vy; az[k] = vz;
        accept |= (ok ? 1u : 0u) << k;
    }

    int wcnt = 0;
    for (int k = 0; k < nr; ++k)
        wcnt += (int)__popcll(__ballot((accept >> k) & 1u));
    if (lane == 0) wtot[wave] = wcnt;
    __syncthreads();
    if (tid == 0) {
        wbase[0] = 0;
        wbase[1] = wtot[0];
        wbase[2] = wtot[0] + wtot[1];
    }
    __syncthreads();
    const int n = min(wbase[2], SCAP);

    if (tid == 0) actc[lt * NCH + s] = n;
    if (n == 0) return;

    int run = wbase[wave];
    for (int k = 0; k < nr; ++k) {
        const unsigned long long m = __ballot((accept >> k) & 1u);
        if ((accept >> k) & 1u) {
            const int pos = run + (int)__popcll(m & ((1ull << lane) - 1ull));
            if (pos < SCAP)
                sa[pos] = make_float4(ax[k], ay[k], az[k], 0.0f);
        }
        run += (int)__popcll(m);
    }
    __syncthreads();

    // ---- eval: 4 cells/thread (x,x+4)x(z,z+4); culled body (R18) ----
    const int lx = tid >> 5;
    const int ly = (tid >> 2) & 7;
    const int lz = tid & 3;

    const float r15sq = (1.5f * r) * (1.5f * r);
    const float rr    = r * r;
    const float E2    = 7.3890562f;
    const float c2a   = 4.0f / (E2 * rr);
    const float c2b   = 12.0f / (E2 * r);
    const float c2c   = 9.0f / E2;
    const float n2orr = -2.0f / rr;

    const float px0 = 0.5f * (float)(tx * 8 + lx);
    const float py  = 0.5f * (float)(ty * 8 + ly);
    const float pz0 = 0.5f * (float)(tz * 8 + lz);

    float acc00 = 0.0f, acc01 = 0.0f, acc10 = 0.0f, acc11 = 0.0f;

    for (int j = 0; j < n; ++j) {
        const float4 a = sa[j];               // one b128 LDS broadcast
        const float dy  = a.y - py;
        const float sy  = dy * dy;
        const float dz0 = a.z - pz0, dz1 = dz0 - 2.0f;
        const float sz0 = fmaf(dz0, dz0, sy), sz1 = fmaf(dz1, dz1, sy);
        const float dx0 = a.x - px0, dx1 = dx0 - 2.0f;
        const float xx0 = dx0 * dx0, xx1 = dx1 * dx1;
        const float d200 = xx0 + sz0, d201 = xx0 + sz1;
        const float d210 = xx1 + sz0, d211 = xx1 + sz1;
        const bool h00 = d200 < r15sq, h01 = d201 < r15sq;
        const bool h10 = d210 < r15sq, h11 = d211 < r15sq;
        if (__ballot(h00 | h01 | h10 | h11) == 0ull) continue;  // wave cull
        if (h00) { const float d = sqrtf(d200);
            acc00 += (d < r) ? __expf(n2orr * d200)
                             : fmaf(c2a, d200, fmaf(-c2b, d, c2c)); }
        if (h01) { const float d = sqrtf(d201);
            acc01 += (d < r) ? __expf(n2orr * d201)
                             : fmaf(c2a, d201, fmaf(-c2b, d, c2c)); }
        if (h10) { const float d = sqrtf(d210);
            acc10 += (d < r) ? __expf(n2orr * d210)
                             : fmaf(c2a, d210, fmaf(-c2b, d, c2c)); }
        if (h11) { const float d = sqrtf(d211);
            acc11 += (d < r) ? __expf(n2orr * d211)
                             : fmaf(c2a, d211, fmaf(-c2b, d, c2c)); }
    }

    float* __restrict__ cp = copies + ((size_t)lt * NCH + s) * 512;
    cp[((lx      * 8) + ly) * 8 + lz]      = acc00;
    cp[((lx      * 8) + ly) * 8 + lz + 4]  = acc01;
    cp[(((lx + 4) * 8) + ly) * 8 + lz]     = acc10;
    cp[(((lx + 4) * 8) + ly) * 8 + lz + 4] = acc11;
}

// Dispatch 3: one block per (tile,type). Sum stored segments (count>0) in
// fixed order; write all 512 cells exactly once (zeros for inactive tiles).
__global__ __launch_bounds__(256) void reduce_kernel(
    const int* __restrict__ actc, const float* __restrict__ copies,
    float* __restrict__ out)
{
    const int type = blockIdx.y;
    const int t = blockIdx.x;
    const int lt = type * NTILES + t;
    const int tid = threadIdx.x;

    __shared__ int segn[NCH];
    if (tid < NCH) segn[tid] = actc[lt * NCH + tid];
    __syncthreads();

    const float* __restrict__ cp = copies + ((size_t)lt * NCH) * 512;
    float o0 = 0.0f, o1 = 0.0f;
    #pragma unroll
    for (int ss = 0; ss < NCH; ++ss) {
        if (segn[ss] > 0) {
            o0 += cp[(size_t)ss * 512 + tid];
            o1 += cp[(size_t)ss * 512 + 256 + tid];
        }
    }

    const int tx = t / (NT * NT);
    const int ty = (t / NT) % NT;
    const int tz = t % NT;
    const int lx = tid >> 6;
    const int ly = (tid >> 3) & 7;
    const int lz = tid & 7;
    const int X0 = tx * 8 + lx;
    const int Y  = ty * 8 + ly;
    const int Z  = tz * 8 + lz;
    float* __restrict__ o = out + (size_t)type * NG * NG * NG;
    o[((X0      * NG) + Y) * NG + Z] = o0;
    o[(((X0 + 4) * NG) + Y) * NG + Z] = o1;
}

extern "C" void kernel_launch(void* const* d_in, const int* in_sizes, int n_in,
                              void* d_out, int out_size, void* d_ws, size_t ws_size,
                              hipStream_t stream) {
    const float* vC = (const float*)d_in[0];
    const float* vN = (const float*)d_in[1];
    const float* vO = (const float*)d_in[2];
    float* out = (float*)d_out;

    int*   ccnt   = (int*)d_ws;
    float* cpos   = (float*)((char*)d_ws + CPOS_OFF);
    int*   actc   = (int*)((char*)d_ws + ACTC_OFF);
    float* copies = (float*)((char*)d_ws + COPIES_OFF);

    const int natoms = in_sizes[0] / 3;   // 16384

    dim3 pgrid(NCH, 3, 1);
    prep_kernel<<<pgrid, 512, 0, stream>>>(vC, vN, vO, ccnt, cpos, natoms);

    dim3 ggrid(NTILES * NCH, 3, 1);
    gather_scan<<<ggrid, 128, 0, stream>>>(ccnt, cpos, actc, copies);

    dim3 rgrid(NTILES, 3, 1);
    reduce_kernel<<<rgrid, 256, 0, stream>>>(actc, copies, out);
}

// Round 20
// 39.755 us; speedup vs baseline: 1.2430x; 1.2430x over previous
//
#include <hip/hip_runtime.h>

#define NG 48
#define NT 6                    // 4 A tiles per axis (8 cells)
#define NTILES (NT * NT * NT)   // 216
#define CHUNK 512               // atoms per bin block
#define NCHUNK 32               // 16384 / 512
#define SUBCAP 96               // per-(tile,chunk) capacity; lambda ~32
#define NSEG 8                  // gather segments = chunk groups of 4
#define CPSEG (NCHUNK / NSEG)   // 4 chunks per segment
// ws layout:
//   [0,      82944)   int cntc[3*216][NCHUNK]
//   [131072, +3.98M)  u16 lists[3*216][NCHUNK][SUBCAP]
//   [8MiB,   +10.6M)  float copies[3*216][NSEG][512]
#define LISTS_OFF  131072
#define COPIES_OFF (8u << 20)

__device__ __forceinline__ float type_r(int type) {
    return (type == 0) ? 1.7f : ((type == 1) ? 1.55f : 1.52f);
}

// Phase 1 (proven, R13): one block per (512-atom chunk, type). LDS histogram
// assigns each (atom,tile) insertion a slot in the chunk-PRIVATE sub-list ->
// plain global stores only (no global atomics, no memset). Stores counts.
__global__ __launch_bounds__(512) void bin_kernel(
    const float* __restrict__ vC, const float* __restrict__ vN,
    const float* __restrict__ vO, int* __restrict__ cntc,
    unsigned short* __restrict__ lists, int natoms)
{
    const int type  = blockIdx.y;
    const int chunk = blockIdx.x;
    const float r = type_r(type);
    const float b = 1.5f * r + 1e-3f;
    const float* __restrict__ vecs = (type == 0) ? vC : ((type == 1) ? vN : vO);
    const int tid  = threadIdx.x;
    const int atom = chunk * CHUNK + tid;

    __shared__ int lfill[NTILES];
    if (tid < NTILES) lfill[tid] = 0;
    __syncthreads();

    int x0 = 1, x1 = 0, y0 = 1, y1 = 0, z0 = 1, z1 = 0;
    if (atom < natoms) {
        const float vx = vecs[3 * atom + 0] + 23.5f;  // vec = raw + 24 - 0.5
        const float vy = vecs[3 * atom + 1] + 23.5f;
        const float vz = vecs[3 * atom + 2] + 23.5f;
        // tile t intersects the 1.5r halo iff 4t > v - b - 3.5 and 4t < v + b
        x0 = max(0,      (int)floorf((vx - 3.5f - b) * 0.25f) + 1);
        x1 = min(NT - 1, (int)ceilf ((vx + b)        * 0.25f) - 1);
        y0 = max(0,      (int)floorf((vy - 3.5f - b) * 0.25f) + 1);
        y1 = min(NT - 1, (int)ceilf ((vy + b)        * 0.25f) - 1);
        z0 = max(0,      (int)floorf((vz - 3.5f - b) * 0.25f) + 1);
        z1 = min(NT - 1, (int)ceilf ((vz + b)        * 0.25f) - 1);
    }
    const bool has = (x0 <= x1) & (y0 <= y1) & (z0 <= z1);

    if (has)
        for (int tx = x0; tx <= x1; ++tx)
            for (int ty = y0; ty <= y1; ++ty)
                for (int tz = z0; tz <= z1; ++tz) {
                    const int tl = (tx * NT + ty) * NT + tz;
                    const int p  = atomicAdd(&lfill[tl], 1);   // LDS only
                    if (p < SUBCAP)
                        lists[((size_t)(type * NTILES + tl) * NCHUNK + chunk)
                              * SUBCAP + p] = (unsigned short)atom;
                }
    __syncthreads();

    if (tid < NTILES)
        cntc[(type * NTILES + tid) * NCHUNK + chunk] = min(lfill[tid], SUBCAP);
}

// One-atom culled evaluation (2 cells: x and x+4).
#define PROCESS(a)                                                           \
    {                                                                        \
        const float dy  = (a).y - py;                                        \
        const float dz  = (a).z - pz;                                        \
        const float syz = fmaf(dy, dy, dz * dz);                             \
        const float dx0 = (a).x - px0;                                       \
        const float dx1 = (a).x - px1;                                       \
        const float d2a = fmaf(dx0, dx0, syz);                               \
        const float d2b = fmaf(dx1, dx1, syz);                               \
        const bool h0 = d2a < r15sq;                                         \
        const bool h1 = d2b < r15sq;                                         \
        if (__ballot(h0 | h1) != 0ull) {                                     \
            if (h0) { const float d = sqrtf(d2a);                            \
                acc0 += (d < r) ? __expf(n2orr * d2a)                        \
                                : fmaf(c2a, d2a, fmaf(-c2b, d, c2c)); }      \
            if (h1) { const float d = sqrtf(d2b);                            \
                acc1 += (d < r) ? __expf(n2orr * d2b)                        \
                                : fmaf(c2a, d2b, fmaf(-c2b, d, c2c)); }      \
        }                                                                    \
    }

// Phase 2 (R13 structure + pipelined eval): one 256-thread block per
// (segment, tile, type), segment-major. Segment s owns chunks [4s, 4s+4).
// Eval loop: hand-unrolled x2 with 2-deep register prefetch of sa[] so the
// next pair's LDS latency hides under the current pair's ballot+masked eval.
__global__ __launch_bounds__(256) void gather_seg(
    const float* __restrict__ vC, const float* __restrict__ vN,
    const float* __restrict__ vO, const int* __restrict__ cntc,
    const unsigned short* __restrict__ lists, float* __restrict__ copies)
{
    const int type = blockIdx.y;
    const int s = blockIdx.x / NTILES;        // segment-major spread
    const int t = blockIdx.x - s * NTILES;
    const int lt = type * NTILES + t;

    __shared__ int ps[CPSEG + 1];
    __shared__ float4 sa[256];

    const int tid = threadIdx.x;
    if (tid == 0) {
        int acc = 0;
        ps[0] = 0;
        #pragma unroll
        for (int c = 0; c < CPSEG; ++c) {
            acc += cntc[lt * NCHUNK + s * CPSEG + c];
            ps[c + 1] = acc;
        }
    }
    __syncthreads();
    const int total = ps[CPSEG];
    if (total == 0) return;                   // empty segment: no work, no store

    const float r = type_r(type);
    const float* __restrict__ vecs = (type == 0) ? vC : ((type == 1) ? vN : vO);

    const int tx = t / (NT * NT);
    const int ty = (t / NT) % NT;
    const int tz = t % NT;
    const int lx  = tid >> 6;          // 0..3 -> cells x and x+4
    const int ly  = (tid >> 3) & 7;
    const int lz  = tid & 7;

    const float b      = 1.5f * r;
    const float r15sq  = b * b;
    const float rr     = r * r;
    const float E2     = 7.3890562f;
    const float c2a    = 4.0f / (E2 * rr);
    const float c2b    = 12.0f / (E2 * r);
    const float c2c    = 9.0f / E2;
    const float n2orr  = -2.0f / rr;

    const float px0 = 0.5f * (float)(tx * 8 + lx);
    const float px1 = px0 + 2.0f;
    const float py  = 0.5f * (float)(ty * 8 + ly);
    const float pz  = 0.5f * (float)(tz * 8 + lz);

    const unsigned short* __restrict__ lbase =
        lists + ((size_t)lt * NCHUNK + s * CPSEG) * SUBCAP;

    float acc0 = 0.0f, acc1 = 0.0f;

    for (int base = 0; base < total; base += 256) {
        const int m = min(256, total - base);
        if (tid < m) {
            const int g = base + tid;
            int c = (ps[2] <= g) ? 2 : 0;               // 2-step search over 4
            c += (ps[c + 1] <= g) ? 1 : 0;
            const int idx = (int)lbase[(size_t)c * SUBCAP + (g - ps[c])];
            sa[tid] = make_float4(vecs[3 * idx + 0] + 23.5f,
                                  vecs[3 * idx + 1] + 23.5f,
                                  vecs[3 * idx + 2] + 23.5f, 0.0f);
        }
        __syncthreads();

        // ---- pipelined eval: unroll x2, 2-deep register prefetch ----
        float4 aA = sa[0];
        float4 aB = sa[(m > 1) ? 1 : 0];
        for (int j = 0; j < m; j += 2) {
            const int p2 = (j + 2 < m) ? j + 2 : 0;     // clamped prefetch
            const int p3 = (j + 3 < m) ? j + 3 : 0;
            const float4 aC = sa[p2];                   // issued before use
            const float4 aD = sa[p3];
            PROCESS(aA);
            if (j + 1 < m) PROCESS(aB);                 // wave-uniform guard
            aA = aC;
            aB = aD;
        }
        __syncthreads();
    }

    float* __restrict__ cp = copies + ((size_t)lt * NSEG + s) * 512;
    cp[tid]       = acc0;
    cp[tid + 256] = acc1;
}

// Phase 3 (proven, R13): one block per (tile,type). Derives per-segment
// activity from chunk counts, sums stored segments in fixed order, writes
// the tile's 512 output cells once (zeros for inactive tiles).
__global__ __launch_bounds__(256) void reduce_kernel(
    const int* __restrict__ cntc, const float* __restrict__ copies,
    float* __restrict__ out)
{
    const int type = blockIdx.y;
    const int t = blockIdx.x;
    const int lt = type * NTILES + t;
    const int tid = threadIdx.x;

    __shared__ int segact[NSEG];
    if (tid < NSEG) {
        int acc = 0;
        #pragma unroll
        for (int c = 0; c < CPSEG; ++c)
            acc += cntc[lt * NCHUNK + tid * CPSEG + c];
        segact[tid] = acc;
    }
    __syncthreads();

    const float* __restrict__ cp = copies + ((size_t)lt * NSEG) * 512;
    float o0 = 0.0f, o1 = 0.0f;
    #pragma unroll
    for (int ss = 0; ss < NSEG; ++ss) {
        if (segact[ss] > 0) {
            o0 += cp[(size_t)ss * 512 + tid];
            o1 += cp[(size_t)ss * 512 + 256 + tid];
        }
    }

    const int tx = t / (NT * NT);
    const int ty = (t / NT) % NT;
    const int tz = t % NT;
    const int lx  = tid >> 6;
    const int ly  = (tid >> 3) & 7;
    const int lz  = tid & 7;
    const int X0 = tx * 8 + lx;
    const int Y  = ty * 8 + ly;
    const int Z  = tz * 8 + lz;
    float* __restrict__ o = out + (size_t)type * NG * NG * NG;
    o[((X0      * NG) + Y) * NG + Z] = o0;
    o[(((X0 + 4) * NG) + Y) * NG + Z] = o1;
}

extern "C" void kernel_launch(void* const* d_in, const int* in_sizes, int n_in,
                              void* d_out, int out_size, void* d_ws, size_t ws_size,
                              hipStream_t stream) {
    const float* vC = (const float*)d_in[0];
    const float* vN = (const float*)d_in[1];
    const float* vO = (const float*)d_in[2];
    float* out = (float*)d_out;

    int* cntc = (int*)d_ws;
    unsigned short* lists = (unsigned short*)((char*)d_ws + LISTS_OFF);
    float* copies = (float*)((char*)d_ws + COPIES_OFF);

    const int natoms = in_sizes[0] / 3;               // 16384
    const int nchunk = (natoms + CHUNK - 1) / CHUNK;  // 32 == NCHUNK

    dim3 bgrid(nchunk, 3, 1);
    bin_kernel<<<bgrid, CHUNK, 0, stream>>>(vC, vN, vO, cntc, lists, natoms);

    dim3 ggrid(NTILES * NSEG, 3, 1);
    gather_seg<<<ggrid, 256, 0, stream>>>(vC, vN, vO, cntc, lists, copies);

    dim3 rgrid(NTILES, 3, 1);
    reduce_kernel<<<rgrid, 256, 0, stream>>>(cntc, copies, out);
}